// Round 6
// baseline (354.846 us; speedup 1.0000x reference)
//
#include <hip/hip_runtime.h>

// ---------------------------------------------------------------------------
// LinearAttention (b=8, c=512, l=4096, heads=8, dim_head=64)
//   xn = rmsnorm_ch(x, g_in); qkv = W_qkv @ xn
//   q = softmax_d(q)*scale; k = softmax_l(k)
//   ctx = k v^T; out = ctx^T q; o = rmsnorm_ch(W_out @ out + b_out) + x
// GEMM v6: A (weights) streamed GLOBAL->VGPR (L1/L2 broadcast absorbs the 4x
// wave duplication that made LDS the bottleneck: 192KB/tile LDS reads -> 64KB).
// B-only LDS (64KB, 2-buf, XOR swizzle, DMA-staged, counted vmcnt(20)/tile).
// A loads are plain C++ (compiler inserts precise counted vmcnt), one tile
// ahead into double fragment sets. 8 waves, 256x256 tile, 16x16x32 MFMA.
// ---------------------------------------------------------------------------

#define BB 8
#define CC 512
#define LL 4096
#define HH 8
#define DH 64
#define TC 1536

__device__ __constant__ const float SQRT_C = 22.62741699796952f;   // sqrt(512)
#define SCALE_Q 0.125f                                             // 64^-0.5

typedef unsigned short bfr_t;
typedef __attribute__((ext_vector_type(8))) short short8;
typedef __attribute__((ext_vector_type(4))) float f32x4;

__device__ __forceinline__ float bf2f(bfr_t v) {
  union { unsigned u; float f; } c; c.u = ((unsigned)v) << 16; return c.f;
}
__device__ __forceinline__ bfr_t f2bf(float f) {
  union { float f; unsigned u; } c; c.f = f;
  unsigned u = c.u + 0x7fffu + ((c.u >> 16) & 1u);   // RNE, ignores NaN edge
  return (bfr_t)(u >> 16);
}

__device__ __forceinline__ void load_lds16(const bfr_t* g, short* l) {
  __builtin_amdgcn_global_load_lds(
      (const __attribute__((address_space(1))) void*)g,
      (__attribute__((address_space(3))) void*)l, 16, 0, 0);
}

// -------- f32 -> bf16 convert (both weights, vectorized x8, 1 launch) ------
__global__ __launch_bounds__(256) void conv_bf16_2(
    const float* __restrict__ in1, bfr_t* __restrict__ o1, int n1,
    const float* __restrict__ in2, bfr_t* __restrict__ o2, int n2) {
  int i8 = (blockIdx.x * 256 + threadIdx.x) * 8;
  const float* src;
  bfr_t* dst;
  if (i8 < n1) { src = in1 + i8; dst = o1 + i8; }
  else {
    int j8 = i8 - n1;
    if (j8 >= n2) return;
    src = in2 + j8; dst = o2 + j8;
  }
  f32x4 a = *(const f32x4*)src;
  f32x4 b = *(const f32x4*)(src + 4);
  union { short s[8]; f32x4 v; } pk;
#pragma unroll
  for (int u = 0; u < 4; ++u) { pk.s[u] = (short)f2bf(a[u]); pk.s[u + 4] = (short)f2bf(b[u]); }
  *(f32x4*)dst = pk.v;
}

// ------ fused channel-RMSNorm + transpose: x[b][c][l] -> xt[b][l][c] -------
__global__ __launch_bounds__(256) void fused_norm_transpose(
    const float* __restrict__ x, const float* __restrict__ g,
    bfr_t* __restrict__ xt) {
  __shared__ float tile[64][65];
  __shared__ float red[4][64];
  __shared__ float invn_s[64];
  int b = blockIdx.y, l0 = blockIdx.x * 64;
  int t = threadIdx.x, ll = t & 63, cg = t >> 6;
  const float* xb = x + (size_t)b * CC * LL + l0;
  float vals[8][16];
  float ss = 0.f;
#pragma unroll
  for (int ch = 0; ch < 8; ++ch) {
    int c0 = ch * 64;
#pragma unroll
    for (int i = 0; i < 16; ++i) {
      int c = i * 4 + cg;                       // chunk-local channel
      float v = xb[(size_t)(c0 + c) * LL + ll];
      vals[ch][i] = v;
      ss += v * v;
    }
  }
  red[cg][ll] = ss;
  __syncthreads();
  if (cg == 0) {
    float s = red[0][ll] + red[1][ll] + red[2][ll] + red[3][ll];
    invn_s[ll] = SQRT_C / fmaxf(sqrtf(s), 1e-12f);
  }
  __syncthreads();
  int lw = t >> 2, ccw = (t & 3) * 16;
  float iv = invn_s[lw];
#pragma unroll
  for (int ch = 0; ch < 8; ++ch) {
    int c0 = ch * 64;
#pragma unroll
    for (int i = 0; i < 16; ++i) tile[i * 4 + cg][ll] = vals[ch][i];
    __syncthreads();
    union { short s[16]; f32x4 v[2]; } pk;
#pragma unroll
    for (int u = 0; u < 16; ++u) {
      int c = ccw + u;
      pk.s[u] = (short)f2bf(tile[c][lw] * g[c0 + c] * iv);
    }
    bfr_t* dst = xt + ((size_t)b * LL + l0 + lw) * CC + c0 + ccw;
    *(f32x4*)dst = pk.v[0];
    *(f32x4*)(dst + 8) = pk.v[1];
    __syncthreads();
  }
}

// --------------- 256x256 bf16 GEMM, A-from-global, B-only LDS --------------
// C[b][m][n] = sum_k A[m][k] * Bt[b][n][k] (+ bias[m]); A:[M][512], Bt:[B][L][512]
// 8 waves (2M x 4N), per-wave 128x64 out. LDS: [2 buf][256][64] B = 64 KB.
// Per K-tile: {ds_read 8 B-frags, lgkm, barrier, MFMA half0 (aS0 x bS),
// load A0(kt+1) global->reg, MFMA half1 (aS1 x bS), load A1(kt+1),
// stage B(kt+2) DMA, vmcnt(20), barrier}. A-load waits inserted by compiler.
#define NT 8                                      // K-tiles (K=512, BK=64)

#define CFENCE asm volatile("" ::: "memory")
#define LGKM0 asm volatile("s_waitcnt lgkmcnt(0)" ::: "memory")
#define VMCW(N) asm volatile("s_waitcnt vmcnt(" #N ")" ::: "memory")
#define SB    __builtin_amdgcn_sched_barrier(0)
#define BAR   do { CFENCE; __builtin_amdgcn_s_barrier(); CFENCE; } while (0)
#define PRIO1 __builtin_amdgcn_s_setprio(1)
#define PRIO0 __builtin_amdgcn_s_setprio(0)

#define DSR(dst, addr, LIT) \
  asm volatile("ds_read_b128 %0, %1 offset:" #LIT : "=v"(dst) : "v"(addr))

// 8 B-fragment reads (j=0..3 x k-slot 0/1) from buf 0 / buf 1
#define RD_BS0() do {                                      \
    DSR(bS[0], bA0, 0);    DSR(bS[1], bA1, 0);             \
    DSR(bS[2], bA0, 2048); DSR(bS[3], bA1, 2048);          \
    DSR(bS[4], bA0, 4096); DSR(bS[5], bA1, 4096);          \
    DSR(bS[6], bA0, 6144); DSR(bS[7], bA1, 6144); } while (0)
#define RD_BS1() do {                                      \
    DSR(bS[0], bA0, 32768); DSR(bS[1], bA1, 32768);        \
    DSR(bS[2], bA0, 34816); DSR(bS[3], bA1, 34816);        \
    DSR(bS[4], bA0, 36864); DSR(bS[5], bA1, 36864);        \
    DSR(bS[6], bA0, 38912); DSR(bS[7], bA1, 38912); } while (0)

// A fragment loads, half H (row group), tile J: global -> registers
#define LD_A(S, H, J) do {                                                   \
    _Pragma("unroll") for (int i_ = 0; i_ < 4; ++i_) {                       \
      S[i_ * 2 + 0] = *(const short8*)(pA + (size_t)((H) * 64 + i_ * 16) * 512 + (J) * 64);      \
      S[i_ * 2 + 1] = *(const short8*)(pA + (size_t)((H) * 64 + i_ * 16) * 512 + (J) * 64 + 32); \
    } } while (0)

// 32 MFMA: row-half QM (aS set) x all 4 col groups x 2 k-slots
#define MMA_H(QM, AS) do {                                                   \
    PRIO1;                                                                   \
    _Pragma("unroll") for (int i_ = 0; i_ < 4; ++i_)                         \
      _Pragma("unroll") for (int j_ = 0; j_ < 4; ++j_) {                     \
        acc[(QM)*4+i_][j_] = __builtin_amdgcn_mfma_f32_16x16x32_bf16(        \
            AS[i_*2+0], bS[j_*2+0], acc[(QM)*4+i_][j_], 0, 0, 0);            \
        acc[(QM)*4+i_][j_] = __builtin_amdgcn_mfma_f32_16x16x32_bf16(        \
            AS[i_*2+1], bS[j_*2+1], acc[(QM)*4+i_][j_], 0, 0, 0);            \
      }                                                                      \
    PRIO0; } while (0)

// cooperative B stage: 32 KB tile, 4 x load_lds16 per wave (chunk = 8 rows)
#define STAGE_B(J, D) do {                                                   \
    _Pragma("unroll") for (int u_ = 0; u_ < 4; ++u_)                         \
      load_lds16(pB + (size_t)(J) * 64 + (size_t)(wid * 4 + u_) * 4096,      \
                 Bls + (D) * 16384 + (wid * 4 + u_) * 512);                  \
  } while (0)

#define TILE(KT, RD) do {                                                    \
    RD(); LGKM0; SB; BAR;                                                    \
    MMA_H(0, aS0); SB;                                                       \
    if ((KT) < NT - 1) LD_A(aS0, 0, (KT) + 1);                               \
    SB;                                                                      \
    MMA_H(1, aS1); SB;                                                       \
    if ((KT) < NT - 1) LD_A(aS1, 1, (KT) + 1);                               \
    if ((KT) < NT - 2) STAGE_B((KT) + 2, (KT) & 1);                          \
    SB;                                                                      \
    if ((KT) == NT - 2)     { VMCW(16); BAR; }                               \
    else if ((KT) < NT - 2) { VMCW(20); BAR; }                               \
  } while (0)

__global__ __launch_bounds__(512, 2) void gemm256(
    const bfr_t* __restrict__ A, const bfr_t* __restrict__ Bt,
    bfr_t* __restrict__ Cout, const float* __restrict__ bias, int M) {
  __shared__ short lds[32768];          // 64 KB: B only [2 buf][256][64]
  short* Bls = lds;

  // --- bijective XCD-chunk swizzle (nwg % 8 == 0), y fastest in-chunk ---
  int nwg = gridDim.x;
  int gy = M >> 8;                      // M-blocks (6 for QKV, 2 for Wout)
  int bid = blockIdx.x;
  int logical = (bid & 7) * (nwg >> 3) + (bid >> 3);
  int perz = (LL / 256) * gy;
  int bz = logical / perz;
  int rem = logical - bz * perz;
  int bx = rem / gy;
  int by = rem - bx * gy;

  int m0 = by * 256, n0 = bx * 256;
  int t = threadIdx.x, lane = t & 63, wid = t >> 6;
  int quad = lane >> 4, r16 = lane & 15;
  int wm = wid >> 2, wn = wid & 3;
  // B staging source offset: row (lane>>3), pre-swizzled granule (l&7)^(l>>3)
  int soff = (lane >> 3) * 512 + (((lane & 7) ^ (lane >> 3)) * 8);
  // B ds_read swizzled granule slots: slot = k-granule ^ (row&7); row&7==lane&7
  int slot0 = (quad ^ (lane & 7));              // k 0..31
  int slot1 = ((4 + quad) ^ (lane & 7));        // k 32..63

  unsigned lb = (unsigned)(uintptr_t)(__attribute__((address_space(3))) short*)lds;
  unsigned bA0 = lb + (unsigned)((wn * 64 + r16) * 128 + slot0 * 16);
  unsigned bA1 = lb + (unsigned)((wn * 64 + r16) * 128 + slot1 * 16);

  const bfr_t* pB = Bt + (size_t)bz * LL * 512 + (size_t)n0 * 512 + soff;
  // A fragment base: row (m0 + wm*128 + r16), k-base quad*8 (no swizzle)
  const bfr_t* pA = A + (size_t)(m0 + wm * 128 + r16) * 512 + quad * 8;

  f32x4 acc[8][4] = {};
  short8 aS0[8], aS1[8];   // row-half 0 / 1; [i*2 + kslot]
  short8 bS[8];            // [j*2 + kslot]

  // ---- prologue: stage B tiles 0,1; load A tile 0 ----
  STAGE_B(0, 0);
  STAGE_B(1, 1);
  LD_A(aS0, 0, 0);
  LD_A(aS1, 1, 0);
  VMCW(20);                // retire B(0) DMA (24 outstanding -> <=20)
  BAR;

  TILE(0, RD_BS0); TILE(1, RD_BS1); TILE(2, RD_BS0); TILE(3, RD_BS1);
  TILE(4, RD_BS0); TILE(5, RD_BS1); TILE(6, RD_BS0); TILE(7, RD_BS1);

  // ---- epilogue: C write (+bias) ----
  bfr_t* Cb = Cout + (size_t)bz * M * LL;
  int crow = m0 + wm * 128 + quad * 4;
  int ccol = n0 + wn * 64 + r16;
#pragma unroll
  for (int am = 0; am < 8; ++am) {
    int rbase = crow + (am >> 2) * 64 + (am & 3) * 16;
#pragma unroll
    for (int reg = 0; reg < 4; ++reg) {
      int row = rbase + reg;
      float bi = bias ? bias[row] : 0.f;
#pragma unroll
      for (int an = 0; an < 4; ++an) {
        int col = ccol + an * 16;
        Cb[(size_t)row * LL + col] = f2bf(acc[am][an][reg] + bi);
      }
    }
  }
}

// --------- context partials via MFMA: ctx_p[bh][s][d][e], n split 8 ---------
__global__ __launch_bounds__(256) void context_mfma(
    const bfr_t* __restrict__ qkv, float* __restrict__ ctx_p,
    float* __restrict__ ksum_p) {
  __shared__ float red[4][4096];      // 64 KB: per-wave 64x64 partial
  int s = blockIdx.x, bh = blockIdx.y;
  int b = bh >> 3, h = bh & 7;
  int t = threadIdx.x, lane = t & 63, wid = t >> 6;
  int quad = lane >> 4, r = lane & 15;
  const bfr_t* kb = qkv + ((size_t)b * TC + 512 + h * 64) * LL;   // raw k rows
  const bfr_t* vb = qkv + ((size_t)b * TC + 1024 + h * 64) * LL;  // v rows
  int n_base = s * 512 + wid * 128;
  f32x4 acc[4][4] = {};
  float ps[4] = {};                    // per-lane exp-sum partials, row d=i*16+r
#pragma unroll
  for (int ks = 0; ks < 4; ++ks) {
    int n0 = n_base + ks * 32;
    short8 af[4], bf8[4];
#pragma unroll
    for (int i = 0; i < 4; ++i) {
      union { short s[8]; short8 v8; } uk;
      uk.v8 = *(const short8*)&kb[(size_t)(i * 16 + r) * LL + n0 + quad * 8];
#pragma unroll
      for (int jj = 0; jj < 8; ++jj) {
        float e = __expf(bf2f((bfr_t)uk.s[jj]));
        uk.s[jj] = (short)f2bf(e);
        ps[i] += e;
      }
      af[i] = uk.v8;
      bf8[i] = *(const short8*)&vb[(size_t)(i * 16 + r) * LL + n0 + quad * 8];
    }
#pragma unroll
    for (int i = 0; i < 4; ++i)
#pragma unroll
      for (int j = 0; j < 4; ++j)
        acc[i][j] = __builtin_amdgcn_mfma_f32_16x16x32_bf16(af[i], bf8[j],
                                                            acc[i][j], 0, 0, 0);
  }
  // ksum: reduce across the quad lanes holding the same row d
#pragma unroll
  for (int i = 0; i < 4; ++i) {
    ps[i] += __shfl_xor(ps[i], 16, 64);
    ps[i] += __shfl_xor(ps[i], 32, 64);
  }
  if (quad == 0) {
#pragma unroll
    for (int i = 0; i < 4; ++i) red[wid][i * 16 + r] = ps[i];
  }
  __syncthreads();
  if (t < 64)
    ksum_p[((size_t)bh * 8 + s) * 64 + t] =
        red[0][t] + red[1][t] + red[2][t] + red[3][t];
  __syncthreads();
  // each wave writes its 64x64 partial to its LDS quadrant, then block-sum
#pragma unroll
  for (int i = 0; i < 4; ++i)
#pragma unroll
    for (int j = 0; j < 4; ++j)
#pragma unroll
      for (int reg = 0; reg < 4; ++reg)
        red[wid][(i * 16 + quad * 4 + reg) * 64 + j * 16 + r] = acc[i][j][reg];
  __syncthreads();
  float* out = ctx_p + ((size_t)bh * 8 + s) * 4096;
#pragma unroll
  for (int u = 0; u < 16; ++u) {
    int idx = u * 256 + t;
    out[idx] = red[0][idx] + red[1][idx] + red[2][idx] + red[3][idx];
  }
}

// ------- reduce partials, apply 1/Z -> ctx_bf[bh][d][e] (bf16) --------------
__global__ __launch_bounds__(256) void context_reduce(
    const float* __restrict__ ctx_p, const float* __restrict__ ksum_p,
    bfr_t* __restrict__ ctx_bf) {
  __shared__ float zinv[64];
  int bh = blockIdx.x;
  int t = threadIdx.x;
  if (t < 64) {
    float s = 0.f;
#pragma unroll
    for (int s8 = 0; s8 < 8; ++s8) s += ksum_p[((size_t)bh * 8 + s8) * 64 + t];
    zinv[t] = 1.f / s;
  }
  __syncthreads();
#pragma unroll
  for (int i = 0; i < 16; ++i) {
    int idx = i * 256 + t;            // idx = d*64 + e
    int d = idx >> 6;
    float sum = 0.f;
#pragma unroll
    for (int s = 0; s < 8; ++s) sum += ctx_p[((size_t)bh * 8 + s) * 4096 + idx];
    ctx_bf[(size_t)bh * 4096 + idx] = f2bf(sum * zinv[d]);
  }
}

// --- fused q-softmax + apply: out_t[b][n][h*64+e] = softmax_d(q)^T ctx -----
__global__ __launch_bounds__(256) void apply_fused(
    const bfr_t* __restrict__ qkv, const bfr_t* __restrict__ ctx_bf,
    bfr_t* __restrict__ out_t) {
  int b = blockIdx.z, h = blockIdx.y;
  int t = threadIdx.x, lane = t & 63, wid = t >> 6;
  int quad = lane >> 4, r = lane & 15;
  int n0 = blockIdx.x * 256 + wid * 64;
  const bfr_t* qb = qkv + ((size_t)b * TC + h * 64) * LL;   // q rows [d][n]
  const bfr_t* cb = ctx_bf + (size_t)(b * HH + h) * 4096;   // [d][e]
  float v[4][16];
  float pm[4];
#pragma unroll
  for (int i = 0; i < 4; ++i) {
    pm[i] = -1e30f;
#pragma unroll
    for (int ks = 0; ks < 2; ++ks)
#pragma unroll
      for (int jj = 0; jj < 8; ++jj) {
        float q = bf2f(qb[(size_t)(ks * 32 + quad * 8 + jj) * LL + n0 + i * 16 + r]);
        v[i][ks * 8 + jj] = q;
        pm[i] = fmaxf(pm[i], q);
      }
  }
#pragma unroll
  for (int i = 0; i < 4; ++i) {
    pm[i] = fmaxf(pm[i], __shfl_xor(pm[i], 16, 64));
    pm[i] = fmaxf(pm[i], __shfl_xor(pm[i], 32, 64));
  }
  float psum[4];
#pragma unroll
  for (int i = 0; i < 4; ++i) {
    float s = 0.f;
#pragma unroll
    for (int u = 0; u < 16; ++u) { v[i][u] = __expf(v[i][u] - pm[i]); s += v[i][u]; }
    psum[i] = s;
  }
#pragma unroll
  for (int i = 0; i < 4; ++i) {
    psum[i] += __shfl_xor(psum[i], 16, 64);
    psum[i] += __shfl_xor(psum[i], 32, 64);
  }
  short8 af[2][4];
#pragma unroll
  for (int i = 0; i < 4; ++i) {
    float sc = SCALE_Q / psum[i];
#pragma unroll
    for (int ks = 0; ks < 2; ++ks) {
      union { short s[8]; short8 v8; } u;
#pragma unroll
      for (int jj = 0; jj < 8; ++jj) u.s[jj] = (short)f2bf(v[i][ks * 8 + jj] * sc);
      af[ks][i] = u.v8;
    }
  }
  short8 bfrag[2][4];
#pragma unroll
  for (int ks = 0; ks < 2; ++ks)
#pragma unroll
    for (int j = 0; j < 4; ++j) {
      union { short s[8]; short8 v8; } u;
#pragma unroll
      for (int jj = 0; jj < 8; ++jj)
        u.s[jj] = (short)cb[(ks * 32 + quad * 8 + jj) * 64 + j * 16 + r];
      bfrag[ks][j] = u.v8;
    }
  f32x4 acc[4][4] = {};
#pragma unroll
  for (int ks = 0; ks < 2; ++ks)
#pragma unroll
    for (int i = 0; i < 4; ++i)
#pragma unroll
      for (int j = 0; j < 4; ++j)
        acc[i][j] = __builtin_amdgcn_mfma_f32_16x16x32_bf16(af[ks][i], bfrag[ks][j],
                                                            acc[i][j], 0, 0, 0);
  bfr_t* dst = out_t + (size_t)b * LL * 512 + h * 64;
#pragma unroll
  for (int i = 0; i < 4; ++i)
#pragma unroll
    for (int reg = 0; reg < 4; ++reg) {
      int row = n0 + i * 16 + quad * 4 + reg;
#pragma unroll
      for (int j = 0; j < 4; ++j)
        dst[(size_t)row * 512 + j * 16 + r] = f2bf(acc[i][j][reg]);
    }
}

// ------------- final rmsnorm over c + residual add (single-pass) -----------
__global__ __launch_bounds__(256) void final_norm_res(
    const bfr_t* __restrict__ o, const float* __restrict__ g,
    const float* __restrict__ x, float* __restrict__ out) {
  __shared__ float red[4][64];
  __shared__ float invn[64];
  int b = blockIdx.y, l0 = blockIdx.x * 64;
  int t = threadIdx.x, ll = t & 63, cg = t >> 6;
  const bfr_t* ob = o + (size_t)b * CC * LL + l0 + ll;
  unsigned pk[64];
  float ss = 0.f;
#pragma unroll
  for (int i = 0; i < 64; ++i) {
    int c = cg * 128 + 2 * i;
    unsigned u0 = ob[(size_t)c * LL];
    unsigned u1 = ob[(size_t)(c + 1) * LL];
    float v0 = bf2f((bfr_t)u0), v1 = bf2f((bfr_t)u1);
    ss += v0 * v0 + v1 * v1;
    pk[i] = u0 | (u1 << 16);
  }
  red[cg][ll] = ss;
  __syncthreads();
  if (cg == 0) {
    float s = red[0][ll] + red[1][ll] + red[2][ll] + red[3][ll];
    invn[ll] = SQRT_C / fmaxf(sqrtf(s), 1e-12f);
  }
  __syncthreads();
  float iv = invn[ll];
  const float* xb = x + (size_t)b * CC * LL + l0 + ll;
  float* outb = out + (size_t)b * CC * LL + l0 + ll;
#pragma unroll
  for (int i = 0; i < 64; ++i) {
    int c = cg * 128 + 2 * i;
    float v0 = bf2f((bfr_t)(pk[i] & 0xffffu));
    float v1 = bf2f((bfr_t)(pk[i] >> 16));
    outb[(size_t)c * LL] = v0 * g[c] * iv + xb[(size_t)c * LL];
    outb[(size_t)(c + 1) * LL] = v1 * g[c + 1] * iv + xb[(size_t)(c + 1) * LL];
  }
}

// ---------------------------------------------------------------------------
extern "C" void kernel_launch(void* const* d_in, const int* in_sizes, int n_in,
                              void* d_out, int out_size, void* d_ws,
                              size_t ws_size, hipStream_t stream) {
  const float* x     = (const float*)d_in[0];
  const float* g_in  = (const float*)d_in[1];
  const float* w_qkv = (const float*)d_in[2];
  const float* w_out = (const float*)d_in[3];
  const float* b_out = (const float*)d_in[4];
  const float* g_out = (const float*)d_in[5];
  float* out = (float*)d_out;

  // workspace layout (bytes)
  char* ws = (char*)d_ws;
  const size_t off_wqkv  = 0;                       // 1536*512*2 = 1,572,864
  const size_t off_wout  = 1572864;                 // 512*512*2  =   524,288
  const size_t off_ksump = 2097152;                 // 64*8*64*4  =   131,072
  const size_t off_ctx   = 2260992;                 // 64*64*64*2 =   524,288 (bf16)
  const size_t off_ctxp  = 3309568;                 // 64*8*4096*4 = 8,388,608
  const size_t off_xt    = 11698176;                // 32MB  (xn_t, later out_t)
  const size_t off_qkv   = 45252608;                // 96MB  (later o_bf)
  const size_t ws_need   = 145915904;
  if (ws_size < ws_need) return;   // insufficient scratch -> fail loudly

  bfr_t* wqkv_bf = (bfr_t*)(ws + off_wqkv);
  bfr_t* wout_bf = (bfr_t*)(ws + off_wout);
  float* ksum_p  = (float*)(ws + off_ksump);
  bfr_t* ctx_bf  = (bfr_t*)(ws + off_ctx);
  float* ctxp    = (float*)(ws + off_ctxp);
  bfr_t* xt      = (bfr_t*)(ws + off_xt);    // xn_t then out_t (disjoint lifetimes)
  bfr_t* qkv     = (bfr_t*)(ws + off_qkv);
  bfr_t* o_bf    = (bfr_t*)(ws + off_qkv);   // overwrites dead q/k/v after apply

  // 1. weights -> bf16 (single vectorized launch)
  conv_bf16_2<<<dim3((1536 * 512 + 512 * 512) / 8 / 256), 256, 0, stream>>>(
      w_qkv, wqkv_bf, 1536 * 512, w_out, wout_bf, 512 * 512);
  // 2. fused input rmsnorm + transpose -> bf16 xt
  fused_norm_transpose<<<dim3(LL / 64, BB), 256, 0, stream>>>(x, g_in, xt);
  // 3. qkv = W_qkv @ xn   (A-from-global 256^2 GEMM)
  gemm256<<<dim3((LL / 256) * (TC / 256) * BB), 512, 0, stream>>>(wqkv_bf, xt, qkv, nullptr, TC);
  // 4. context = exp(k) v^T via MFMA (exp + ksum inline), reduce + 1/Z -> bf16
  context_mfma<<<dim3(8, BB * HH), 256, 0, stream>>>(qkv, ctxp, ksum_p);
  context_reduce<<<dim3(BB * HH), 256, 0, stream>>>(ctxp, ksum_p, ctx_bf);
  // 5. fused q-softmax + apply -> out_t (xn_t now dead)
  apply_fused<<<dim3(LL / 256, HH, BB), 256, 0, stream>>>(qkv, ctx_bf, xt);
  // 6. o = W_out @ out + b_out   (qkv fully dead now)
  gemm256<<<dim3((LL / 256) * (CC / 256) * BB), 512, 0, stream>>>(wout_bf, xt, o_bf, b_out, CC);
  // 7. final rmsnorm + residual -> fp32 out
  final_norm_res<<<dim3(LL / 64, BB), 256, 0, stream>>>(o_bf, g_out, x, out);
}

// Round 7
// 299.196 us; speedup vs baseline: 1.1860x; 1.1860x over previous
//
#include <hip/hip_runtime.h>

// ---------------------------------------------------------------------------
// LinearAttention (b=8, c=512, l=4096, heads=8, dim_head=64)
//   xn = rmsnorm_ch(x, g_in); qkv = W_qkv @ xn
//   q = softmax_d(q)*scale; k = softmax_l(k)
//   ctx = k v^T; out = ctx^T q; o = rmsnorm_ch(W_out @ out + b_out) + x
// Round 7: GEMM reverted to round-5 (best: register-pipelined 256x256).
// QKV GEMM split into 3 x M=512 dispatches (diagnostic: un-monopolizes the
// top-5 profile slots so the 190us of un-profiled kernels become visible;
// each part = 256 blocks = exactly 1 round/CU). fnr vectorized (uint/float2).
// apply_fused: exp without max-subtraction (fp32-safe, drops a reduce pass).
// ---------------------------------------------------------------------------

#define BB 8
#define CC 512
#define LL 4096
#define HH 8
#define DH 64
#define TC 1536

__device__ __constant__ const float SQRT_C = 22.62741699796952f;   // sqrt(512)
#define SCALE_Q 0.125f                                             // 64^-0.5

typedef unsigned short bfr_t;
typedef __attribute__((ext_vector_type(8))) short short8;
typedef __attribute__((ext_vector_type(4))) float f32x4;

__device__ __forceinline__ float bf2f(bfr_t v) {
  union { unsigned u; float f; } c; c.u = ((unsigned)v) << 16; return c.f;
}
__device__ __forceinline__ bfr_t f2bf(float f) {
  union { float f; unsigned u; } c; c.f = f;
  unsigned u = c.u + 0x7fffu + ((c.u >> 16) & 1u);   // RNE, ignores NaN edge
  return (bfr_t)(u >> 16);
}

__device__ __forceinline__ void load_lds16(const bfr_t* g, short* l) {
  __builtin_amdgcn_global_load_lds(
      (const __attribute__((address_space(1))) void*)g,
      (__attribute__((address_space(3))) void*)l, 16, 0, 0);
}

// -------- f32 -> bf16 convert (both weights, vectorized x8, 1 launch) ------
__global__ __launch_bounds__(256) void conv_bf16_2(
    const float* __restrict__ in1, bfr_t* __restrict__ o1, int n1,
    const float* __restrict__ in2, bfr_t* __restrict__ o2, int n2) {
  int i8 = (blockIdx.x * 256 + threadIdx.x) * 8;
  const float* src;
  bfr_t* dst;
  if (i8 < n1) { src = in1 + i8; dst = o1 + i8; }
  else {
    int j8 = i8 - n1;
    if (j8 >= n2) return;
    src = in2 + j8; dst = o2 + j8;
  }
  f32x4 a = *(const f32x4*)src;
  f32x4 b = *(const f32x4*)(src + 4);
  union { short s[8]; f32x4 v; } pk;
#pragma unroll
  for (int u = 0; u < 4; ++u) { pk.s[u] = (short)f2bf(a[u]); pk.s[u + 4] = (short)f2bf(b[u]); }
  *(f32x4*)dst = pk.v;
}

// ------ fused channel-RMSNorm + transpose: x[b][c][l] -> xt[b][l][c] -------
__global__ __launch_bounds__(256) void fused_norm_transpose(
    const float* __restrict__ x, const float* __restrict__ g,
    bfr_t* __restrict__ xt) {
  __shared__ float tile[64][65];
  __shared__ float red[4][64];
  __shared__ float invn_s[64];
  int b = blockIdx.y, l0 = blockIdx.x * 64;
  int t = threadIdx.x, ll = t & 63, cg = t >> 6;
  const float* xb = x + (size_t)b * CC * LL + l0;
  float vals[8][16];
  float ss = 0.f;
#pragma unroll
  for (int ch = 0; ch < 8; ++ch) {
    int c0 = ch * 64;
#pragma unroll
    for (int i = 0; i < 16; ++i) {
      int c = i * 4 + cg;                       // chunk-local channel
      float v = xb[(size_t)(c0 + c) * LL + ll];
      vals[ch][i] = v;
      ss += v * v;
    }
  }
  red[cg][ll] = ss;
  __syncthreads();
  if (cg == 0) {
    float s = red[0][ll] + red[1][ll] + red[2][ll] + red[3][ll];
    invn_s[ll] = SQRT_C / fmaxf(sqrtf(s), 1e-12f);
  }
  __syncthreads();
  int lw = t >> 2, ccw = (t & 3) * 16;
  float iv = invn_s[lw];
#pragma unroll
  for (int ch = 0; ch < 8; ++ch) {
    int c0 = ch * 64;
#pragma unroll
    for (int i = 0; i < 16; ++i) tile[i * 4 + cg][ll] = vals[ch][i];
    __syncthreads();
    union { short s[16]; f32x4 v[2]; } pk;
#pragma unroll
    for (int u = 0; u < 16; ++u) {
      int c = ccw + u;
      pk.s[u] = (short)f2bf(tile[c][lw] * g[c0 + c] * iv);
    }
    bfr_t* dst = xt + ((size_t)b * LL + l0 + lw) * CC + c0 + ccw;
    *(f32x4*)dst = pk.v[0];
    *(f32x4*)(dst + 8) = pk.v[1];
    __syncthreads();
  }
}

// ------------- 256x256 register-pipelined sub-phase bf16 GEMM --------------
// C[b][m][n] = sum_k A[m][k] * Bt[b][n][k] (+ bias[m]); A:[M][512], Bt:[B][L][512]
// (round-5 structure, best measured). Mtot = per-batch row stride of Cout so
// the QKV GEMM can be dispatched in 3 independent M=512 parts.
#define NT 8                                      // K-tiles (K=512, BK=64)

__device__ __forceinline__ void stage_half(const bfr_t* g, short* l, int wid) {
  load_lds16(g + (size_t)wid * 8192,        l + wid * 1024);
  load_lds16(g + (size_t)wid * 8192 + 4096, l + wid * 1024 + 512);
}

#define CFENCE asm volatile("" ::: "memory")
#define LGKM0 asm volatile("s_waitcnt lgkmcnt(0)" ::: "memory")
#define VMC0  asm volatile("s_waitcnt vmcnt(0)" ::: "memory")
#define SB    __builtin_amdgcn_sched_barrier(0)
#define BAR   do { CFENCE; __builtin_amdgcn_s_barrier(); CFENCE; } while (0)
#define PRIO1 __builtin_amdgcn_s_setprio(1)
#define PRIO0 __builtin_amdgcn_s_setprio(0)

#define DSR(dst, addr, LIT) \
  asm volatile("ds_read_b128 %0, %1 offset:" #LIT : "=v"(dst) : "v"(addr))

// A-half read: 8 frags (4 row-groups x 2 k-slots)
#define RD_A(S, L0, L1, L2, L3) do {           \
    DSR(S[0], aAs0, L0); DSR(S[1], aAs1, L0);  \
    DSR(S[2], aAs0, L1); DSR(S[3], aAs1, L1);  \
    DSR(S[4], aAs0, L2); DSR(S[5], aAs1, L2);  \
    DSR(S[6], aAs0, L3); DSR(S[7], aAs1, L3); } while (0)
// B col-half read: 4 frags (2 col-16-groups x 2 k-slots)
#define RD_B(S, L0, L1) do {                   \
    DSR(S[0], bBs0, L0); DSR(S[1], bBs1, L0);  \
    DSR(S[2], bBs0, L1); DSR(S[3], bBs1, L1); } while (0)

#define MMA8(QM, QN, AS, BS) do {                                            \
    _Pragma("unroll") for (int i_ = 0; i_ < 4; ++i_)                         \
      _Pragma("unroll") for (int j_ = 0; j_ < 2; ++j_) {                     \
        acc[(QM)*4+i_][(QN)*2+j_] = __builtin_amdgcn_mfma_f32_16x16x32_bf16( \
            AS[i_*2+0], BS[j_*2+0], acc[(QM)*4+i_][(QN)*2+j_], 0, 0, 0);     \
        acc[(QM)*4+i_][(QN)*2+j_] = __builtin_amdgcn_mfma_f32_16x16x32_bf16( \
            AS[i_*2+1], BS[j_*2+1], acc[(QM)*4+i_][(QN)*2+j_], 0, 0, 0);     \
      }                                                                      \
  } while (0)

#define STAGE_T(J, D) do {                                                   \
    stage_half(pA0 + (J) * 64, As + (D) * 16384, wid);                       \
    stage_half(pA1 + (J) * 64, As + (D) * 16384 + 8192, wid);                \
    stage_half(pB0 + (J) * 64, Bs + (D) * 16384, wid);                       \
    stage_half(pB1 + (J) * 64, Bs + (D) * 16384 + 8192, wid);                \
  } while (0)

// ---- one K-tile, current buffer = buf0 (even kt) ----
#define TILE_E(KT) do {                                                      \
    PRIO1; RD_B(bS1, 4096, 6144); MMA8(0, 0, aS0, bS0); PRIO0; LGKM0; SB;    \
    PRIO1; RD_A(aS1, 8192, 10240, 12288, 14336); MMA8(0, 1, aS0, bS1);      \
    PRIO0; LGKM0; SB;                                                        \
    if ((KT) < 7) { VMC0; }                                                  \
    BAR;                                                                     \
    if ((KT) <= 5) STAGE_T((KT) + 2, 0);                                     \
    PRIO1;                                                                   \
    if ((KT) < 7) RD_A(aS0, 32768, 34816, 36864, 38912);                     \
    MMA8(1, 1, aS1, bS1); PRIO0; LGKM0; SB;                                  \
    PRIO1; MMA8(1, 0, aS1, bS0); PRIO0;                                      \
    if ((KT) < 7) RD_B(bS0, 32768, 34816);                                   \
    LGKM0; SB;                                                               \
  } while (0)

// ---- one K-tile, current buffer = buf1 (odd kt) ----
#define TILE_O(KT) do {                                                      \
    PRIO1; RD_B(bS1, 36864, 38912); MMA8(0, 0, aS0, bS0); PRIO0; LGKM0; SB;  \
    PRIO1; RD_A(aS1, 40960, 43008, 45056, 47104); MMA8(0, 1, aS0, bS1);     \
    PRIO0; LGKM0; SB;                                                        \
    if ((KT) < 7) { VMC0; }                                                  \
    BAR;                                                                     \
    if ((KT) <= 5) STAGE_T((KT) + 2, 1);                                     \
    PRIO1;                                                                   \
    if ((KT) < 7) RD_A(aS0, 0, 2048, 4096, 6144);                            \
    MMA8(1, 1, aS1, bS1); PRIO0; LGKM0; SB;                                  \
    PRIO1; MMA8(1, 0, aS1, bS0); PRIO0;                                      \
    if ((KT) < 7) RD_B(bS0, 0, 2048);                                        \
    LGKM0; SB;                                                               \
  } while (0)

__global__ __launch_bounds__(512, 2) void gemm256(
    const bfr_t* __restrict__ A, const bfr_t* __restrict__ Bt,
    bfr_t* __restrict__ Cout, const float* __restrict__ bias, int M, int Mtot) {
  __shared__ short lds[65536];          // 128 KB
  short* As = lds;                      // [2 buf][2 half][128][64]
  short* Bs = lds + 32768;

  // --- bijective XCD-chunk swizzle (nwg % 8 == 0), y fastest in-chunk ---
  int nwg = gridDim.x;
  int gy = M >> 8;                      // M-blocks (2 per 512-part)
  int bid = blockIdx.x;
  int logical = (bid & 7) * (nwg >> 3) + (bid >> 3);
  int perz = (LL / 256) * gy;
  int bz = logical / perz;
  int rem = logical - bz * perz;
  int bx = rem / gy;
  int by = rem - bx * gy;

  int m0 = by * 256, n0 = bx * 256;
  int t = threadIdx.x, lane = t & 63, wid = t >> 6;
  int quad = lane >> 4, r16 = lane & 15;
  int wm = wid >> 2, wn = wid & 3;
  // staging source offset: row (lane>>3), pre-swizzled granule (l&7)^(l>>3)
  int soff = (lane >> 3) * 512 + (((lane & 7) ^ (lane >> 3)) * 8);
  // ds_read swizzled k-granule slots (shorts): slot = gran ^ (row&7), x8
  int slot0 = (quad ^ (lane & 7)) * 8;          // k 0..31
  int slot1 = ((4 + quad) ^ (lane & 7)) * 8;    // k 32..63

  unsigned lb = (unsigned)(uintptr_t)(__attribute__((address_space(3))) short*)lds;
  unsigned aAs0 = lb + (unsigned)(wm * 16384 + r16 * 128 + slot0 * 2);
  unsigned aAs1 = lb + (unsigned)(wm * 16384 + r16 * 128 + slot1 * 2);
  unsigned bbase = 65536u + (unsigned)((wn >> 1) * 16384 + ((wn & 1) * 64 + r16) * 128);
  unsigned bBs0 = lb + bbase + (unsigned)(slot0 * 2);
  unsigned bBs1 = lb + bbase + (unsigned)(slot1 * 2);

  const bfr_t* pA0 = A + (size_t)m0 * 512 + soff;
  const bfr_t* pA1 = pA0 + (size_t)128 * 512;
  const bfr_t* pB0 = Bt + (size_t)bz * LL * 512 + (size_t)n0 * 512 + soff;
  const bfr_t* pB1 = pB0 + (size_t)128 * 512;

  f32x4 acc[8][4] = {};
  short8 aS0[8], aS1[8];
  short8 bS0[4], bS1[4];

  // ---- prologue: stage K-tiles 0 and 1; read q00 frags of tile 0 ----
  STAGE_T(0, 0);
  STAGE_T(1, 1);
  asm volatile("s_waitcnt vmcnt(8)" ::: "memory");   // tile 0 landed
  BAR;
  RD_A(aS0, 0, 2048, 4096, 6144);     // A0(t0)
  RD_B(bS0, 0, 2048);                 // B0(t0)
  LGKM0; SB;

  TILE_E(0); TILE_O(1); TILE_E(2); TILE_O(3);
  TILE_E(4); TILE_O(5); TILE_E(6); TILE_O(7);

  // ---- epilogue: C write (+bias) ----
  bfr_t* Cb = Cout + (size_t)bz * Mtot * LL;
  int crow = m0 + wm * 128 + quad * 4;
  int ccol = n0 + wn * 64 + r16;
#pragma unroll
  for (int am = 0; am < 8; ++am) {
    int rbase = crow + (am >> 2) * 64 + (am & 3) * 16;
#pragma unroll
    for (int reg = 0; reg < 4; ++reg) {
      int row = rbase + reg;
      float bi = bias ? bias[row] : 0.f;
#pragma unroll
      for (int an = 0; an < 4; ++an) {
        int col = ccol + (an >> 1) * 32 + (an & 1) * 16;
        Cb[(size_t)row * LL + col] = f2bf(acc[am][an][reg] + bi);
      }
    }
  }
}

// --------- context partials via MFMA: ctx_p[bh][s][d][e], n split 8 ---------
__global__ __launch_bounds__(256) void context_mfma(
    const bfr_t* __restrict__ qkv, float* __restrict__ ctx_p,
    float* __restrict__ ksum_p) {
  __shared__ float red[4][4096];      // 64 KB: per-wave 64x64 partial
  int s = blockIdx.x, bh = blockIdx.y;
  int b = bh >> 3, h = bh & 7;
  int t = threadIdx.x, lane = t & 63, wid = t >> 6;
  int quad = lane >> 4, r = lane & 15;
  const bfr_t* kb = qkv + ((size_t)b * TC + 512 + h * 64) * LL;   // raw k rows
  const bfr_t* vb = qkv + ((size_t)b * TC + 1024 + h * 64) * LL;  // v rows
  int n_base = s * 512 + wid * 128;
  f32x4 acc[4][4] = {};
  float ps[4] = {};                    // per-lane exp-sum partials, row d=i*16+r
#pragma unroll
  for (int ks = 0; ks < 4; ++ks) {
    int n0 = n_base + ks * 32;
    short8 af[4], bf8[4];
#pragma unroll
    for (int i = 0; i < 4; ++i) {
      union { short s[8]; short8 v8; } uk;
      uk.v8 = *(const short8*)&kb[(size_t)(i * 16 + r) * LL + n0 + quad * 8];
#pragma unroll
      for (int jj = 0; jj < 8; ++jj) {
        float e = __expf(bf2f((bfr_t)uk.s[jj]));
        uk.s[jj] = (short)f2bf(e);
        ps[i] += e;
      }
      af[i] = uk.v8;
      bf8[i] = *(const short8*)&vb[(size_t)(i * 16 + r) * LL + n0 + quad * 8];
    }
#pragma unroll
    for (int i = 0; i < 4; ++i)
#pragma unroll
      for (int j = 0; j < 4; ++j)
        acc[i][j] = __builtin_amdgcn_mfma_f32_16x16x32_bf16(af[i], bf8[j],
                                                            acc[i][j], 0, 0, 0);
  }
  // ksum: reduce across the quad lanes holding the same row d
#pragma unroll
  for (int i = 0; i < 4; ++i) {
    ps[i] += __shfl_xor(ps[i], 16, 64);
    ps[i] += __shfl_xor(ps[i], 32, 64);
  }
  if (quad == 0) {
#pragma unroll
    for (int i = 0; i < 4; ++i) red[wid][i * 16 + r] = ps[i];
  }
  __syncthreads();
  if (t < 64)
    ksum_p[((size_t)bh * 8 + s) * 64 + t] =
        red[0][t] + red[1][t] + red[2][t] + red[3][t];
  __syncthreads();
  // each wave writes its 64x64 partial to its LDS quadrant, then block-sum
#pragma unroll
  for (int i = 0; i < 4; ++i)
#pragma unroll
    for (int j = 0; j < 4; ++j)
#pragma unroll
      for (int reg = 0; reg < 4; ++reg)
        red[wid][(i * 16 + quad * 4 + reg) * 64 + j * 16 + r] = acc[i][j][reg];
  __syncthreads();
  float* out = ctx_p + ((size_t)bh * 8 + s) * 4096;
#pragma unroll
  for (int u = 0; u < 16; ++u) {
    int idx = u * 256 + t;
    out[idx] = red[0][idx] + red[1][idx] + red[2][idx] + red[3][idx];
  }
}

// ------- reduce partials, apply 1/Z -> ctx_bf[bh][d][e] (bf16) --------------
__global__ __launch_bounds__(256) void context_reduce(
    const float* __restrict__ ctx_p, const float* __restrict__ ksum_p,
    bfr_t* __restrict__ ctx_bf) {
  __shared__ float zinv[64];
  int bh = blockIdx.x;
  int t = threadIdx.x;
  if (t < 64) {
    float s = 0.f;
#pragma unroll
    for (int s8 = 0; s8 < 8; ++s8) s += ksum_p[((size_t)bh * 8 + s8) * 64 + t];
    zinv[t] = 1.f / s;
  }
  __syncthreads();
#pragma unroll
  for (int i = 0; i < 16; ++i) {
    int idx = i * 256 + t;            // idx = d*64 + e
    int d = idx >> 6;
    float sum = 0.f;
#pragma unroll
    for (int s = 0; s < 8; ++s) sum += ctx_p[((size_t)bh * 8 + s) * 4096 + idx];
    ctx_bf[(size_t)bh * 4096 + idx] = f2bf(sum * zinv[d]);
  }
}

// --- fused q-softmax + apply: out_t[b][n][h*64+e] = softmax_d(q)^T ctx -----
// exp WITHOUT max-subtraction (|q| small enough for fp32; identical softmax).
__global__ __launch_bounds__(256) void apply_fused(
    const bfr_t* __restrict__ qkv, const bfr_t* __restrict__ ctx_bf,
    bfr_t* __restrict__ out_t) {
  int b = blockIdx.z, h = blockIdx.y;
  int t = threadIdx.x, lane = t & 63, wid = t >> 6;
  int quad = lane >> 4, r = lane & 15;
  int n0 = blockIdx.x * 256 + wid * 64;
  const bfr_t* qb = qkv + ((size_t)b * TC + h * 64) * LL;   // q rows [d][n]
  const bfr_t* cb = ctx_bf + (size_t)(b * HH + h) * 4096;   // [d][e]
  float v[4][16];
  float psum[4];
#pragma unroll
  for (int i = 0; i < 4; ++i) {
    float s = 0.f;
#pragma unroll
    for (int ks = 0; ks < 2; ++ks)
#pragma unroll
      for (int jj = 0; jj < 8; ++jj) {
        float q = bf2f(qb[(size_t)(ks * 32 + quad * 8 + jj) * LL + n0 + i * 16 + r]);
        float e = __expf(q);
        v[i][ks * 8 + jj] = e;
        s += e;
      }
    psum[i] = s;
  }
#pragma unroll
  for (int i = 0; i < 4; ++i) {
    psum[i] += __shfl_xor(psum[i], 16, 64);
    psum[i] += __shfl_xor(psum[i], 32, 64);
  }
  short8 af[2][4];
#pragma unroll
  for (int i = 0; i < 4; ++i) {
    float sc = SCALE_Q / psum[i];
#pragma unroll
    for (int ks = 0; ks < 2; ++ks) {
      union { short s[8]; short8 v8; } u;
#pragma unroll
      for (int jj = 0; jj < 8; ++jj) u.s[jj] = (short)f2bf(v[i][ks * 8 + jj] * sc);
      af[ks][i] = u.v8;
    }
  }
  short8 bfrag[2][4];
#pragma unroll
  for (int ks = 0; ks < 2; ++ks)
#pragma unroll
    for (int j = 0; j < 4; ++j) {
      union { short s[8]; short8 v8; } u;
#pragma unroll
      for (int jj = 0; jj < 8; ++jj)
        u.s[jj] = (short)cb[(ks * 32 + quad * 8 + jj) * 64 + j * 16 + r];
      bfrag[ks][j] = u.v8;
    }
  f32x4 acc[4][4] = {};
#pragma unroll
  for (int ks = 0; ks < 2; ++ks)
#pragma unroll
    for (int i = 0; i < 4; ++i)
#pragma unroll
      for (int j = 0; j < 4; ++j)
        acc[i][j] = __builtin_amdgcn_mfma_f32_16x16x32_bf16(af[ks][i], bfrag[ks][j],
                                                            acc[i][j], 0, 0, 0);
  bfr_t* dst = out_t + (size_t)b * LL * 512 + h * 64;
#pragma unroll
  for (int i = 0; i < 4; ++i)
#pragma unroll
    for (int reg = 0; reg < 4; ++reg) {
      int row = n0 + i * 16 + quad * 4 + reg;
#pragma unroll
      for (int j = 0; j < 4; ++j)
        dst[(size_t)row * 512 + j * 16 + r] = f2bf(acc[i][j][reg]);
    }
}

// ------- final rmsnorm over c + residual add (2-wide vectorized, 2-pass) ----
// thread owns 2 consecutive l: o reads uint (2 bf16), x/out float2.
__global__ __launch_bounds__(256) void final_norm_res(
    const bfr_t* __restrict__ o, const float* __restrict__ g,
    const float* __restrict__ x, float* __restrict__ out) {
  __shared__ float red[4][128];
  __shared__ float invn[128];
  int b = blockIdx.y, l0 = blockIdx.x * 128;
  int t = threadIdx.x, ll = t & 63, cg = t >> 6;
  const bfr_t* ob = o + (size_t)b * CC * LL + l0 + ll * 2;
  float ss0 = 0.f, ss1 = 0.f;
  for (int c = cg * 128; c < cg * 128 + 128; ++c) {
    unsigned u = *(const unsigned*)&ob[(size_t)c * LL];
    float v0 = bf2f((bfr_t)(u & 0xffffu));
    float v1 = bf2f((bfr_t)(u >> 16));
    ss0 += v0 * v0;
    ss1 += v1 * v1;
  }
  red[cg][ll * 2] = ss0;
  red[cg][ll * 2 + 1] = ss1;
  __syncthreads();
  if (t < 128) {
    float s = red[0][t] + red[1][t] + red[2][t] + red[3][t];
    invn[t] = SQRT_C / fmaxf(sqrtf(s), 1e-12f);
  }
  __syncthreads();
  float iv0 = invn[ll * 2], iv1 = invn[ll * 2 + 1];
  const float* xb = x + (size_t)b * CC * LL + l0 + ll * 2;
  float* outb = out + (size_t)b * CC * LL + l0 + ll * 2;
  for (int c = cg * 128; c < cg * 128 + 128; ++c) {
    unsigned u = *(const unsigned*)&ob[(size_t)c * LL];
    float gc = g[c];
    float v0 = bf2f((bfr_t)(u & 0xffffu)) * gc * iv0;
    float v1 = bf2f((bfr_t)(u >> 16)) * gc * iv1;
    float2 xv = *(const float2*)&xb[(size_t)c * LL];
    float2 ov;
    ov.x = v0 + xv.x;
    ov.y = v1 + xv.y;
    *(float2*)&outb[(size_t)c * LL] = ov;
  }
}

// ---------------------------------------------------------------------------
extern "C" void kernel_launch(void* const* d_in, const int* in_sizes, int n_in,
                              void* d_out, int out_size, void* d_ws,
                              size_t ws_size, hipStream_t stream) {
  const float* x     = (const float*)d_in[0];
  const float* g_in  = (const float*)d_in[1];
  const float* w_qkv = (const float*)d_in[2];
  const float* w_out = (const float*)d_in[3];
  const float* b_out = (const float*)d_in[4];
  const float* g_out = (const float*)d_in[5];
  float* out = (float*)d_out;

  // workspace layout (bytes)
  char* ws = (char*)d_ws;
  const size_t off_wqkv  = 0;                       // 1536*512*2 = 1,572,864
  const size_t off_wout  = 1572864;                 // 512*512*2  =   524,288
  const size_t off_ksump = 2097152;                 // 64*8*64*4  =   131,072
  const size_t off_ctx   = 2260992;                 // 64*64*64*2 =   524,288 (bf16)
  const size_t off_ctxp  = 3309568;                 // 64*8*4096*4 = 8,388,608
  const size_t off_xt    = 11698176;                // 32MB  (xn_t, later out_t)
  const size_t off_qkv   = 45252608;                // 96MB  (later o_bf)
  const size_t ws_need   = 145915904;
  if (ws_size < ws_need) return;   // insufficient scratch -> fail loudly

  bfr_t* wqkv_bf = (bfr_t*)(ws + off_wqkv);
  bfr_t* wout_bf = (bfr_t*)(ws + off_wout);
  float* ksum_p  = (float*)(ws + off_ksump);
  bfr_t* ctx_bf  = (bfr_t*)(ws + off_ctx);
  float* ctxp    = (float*)(ws + off_ctxp);
  bfr_t* xt      = (bfr_t*)(ws + off_xt);    // xn_t then out_t (disjoint lifetimes)
  bfr_t* qkv     = (bfr_t*)(ws + off_qkv);
  bfr_t* o_bf    = (bfr_t*)(ws + off_qkv);   // overwrites dead q/k/v after apply

  // 1. weights -> bf16 (single vectorized launch)
  conv_bf16_2<<<dim3((1536 * 512 + 512 * 512) / 8 / 256), 256, 0, stream>>>(
      w_qkv, wqkv_bf, 1536 * 512, w_out, wout_bf, 512 * 512);
  // 2. fused input rmsnorm + transpose -> bf16 xt
  fused_norm_transpose<<<dim3(LL / 64, BB), 256, 0, stream>>>(x, g_in, xt);
  // 3. qkv = W_qkv @ xn -- 3 independent M=512 parts (q, k, v)
  for (int p = 0; p < 3; ++p)
    gemm256<<<dim3((LL / 256) * 2 * BB), 512, 0, stream>>>(
        wqkv_bf + (size_t)p * 512 * 512, xt, qkv + (size_t)p * 512 * LL,
        nullptr, 512, TC);
  // 4. context = exp(k) v^T via MFMA (exp + ksum inline), reduce + 1/Z -> bf16
  context_mfma<<<dim3(8, BB * HH), 256, 0, stream>>>(qkv, ctxp, ksum_p);
  context_reduce<<<dim3(BB * HH), 256, 0, stream>>>(ctxp, ksum_p, ctx_bf);
  // 5. fused q-softmax + apply -> out_t (xn_t now dead)
  apply_fused<<<dim3(LL / 256, HH, BB), 256, 0, stream>>>(qkv, ctx_bf, xt);
  // 6. o = W_out @ out + b_out   (qkv fully dead now)
  gemm256<<<dim3((LL / 256) * 2 * BB), 512, 0, stream>>>(wout_bf, xt, o_bf, b_out, 512, 512);
  // 7. final rmsnorm + residual -> fp32 out
  final_norm_res<<<dim3(LL / 128, BB), 256, 0, stream>>>(o_bf, g_out, x, out);
}

// Round 9
// 278.735 us; speedup vs baseline: 1.2731x; 1.0734x over previous
//
#include <hip/hip_runtime.h>

// ---------------------------------------------------------------------------
// LinearAttention (b=8, c=512, l=4096, heads=8, dim_head=64)
//   xn = rmsnorm_ch(x, g_in); qkv = W_qkv @ xn
//   q = softmax_d(q)*scale; k = softmax_l(k)
//   ctx = k v^T; out = ctx^T q; o = rmsnorm_ch(W_out @ out + b_out) + x
// Round 9: identical to round 8 (container infra failure, no signal).
// QKV single round-5 dispatch; fused gemm_wout_norm (512x128 tile, rmsnorm+
// residual in epilogue, o_bf eliminated); 7 dispatches total.
// ---------------------------------------------------------------------------

#define BB 8
#define CC 512
#define LL 4096
#define HH 8
#define DH 64
#define TC 1536

__device__ __constant__ const float SQRT_C = 22.62741699796952f;   // sqrt(512)
#define SCALE_Q 0.125f                                             // 64^-0.5

typedef unsigned short bfr_t;
typedef __attribute__((ext_vector_type(8))) short short8;
typedef __attribute__((ext_vector_type(4))) float f32x4;

__device__ __forceinline__ float bf2f(bfr_t v) {
  union { unsigned u; float f; } c; c.u = ((unsigned)v) << 16; return c.f;
}
__device__ __forceinline__ bfr_t f2bf(float f) {
  union { float f; unsigned u; } c; c.f = f;
  unsigned u = c.u + 0x7fffu + ((c.u >> 16) & 1u);   // RNE, ignores NaN edge
  return (bfr_t)(u >> 16);
}

__device__ __forceinline__ void load_lds16(const bfr_t* g, short* l) {
  __builtin_amdgcn_global_load_lds(
      (const __attribute__((address_space(1))) void*)g,
      (__attribute__((address_space(3))) void*)l, 16, 0, 0);
}

// -------- f32 -> bf16 convert (both weights, vectorized x8, 1 launch) ------
__global__ __launch_bounds__(256) void conv_bf16_2(
    const float* __restrict__ in1, bfr_t* __restrict__ o1, int n1,
    const float* __restrict__ in2, bfr_t* __restrict__ o2, int n2) {
  int i8 = (blockIdx.x * 256 + threadIdx.x) * 8;
  const float* src;
  bfr_t* dst;
  if (i8 < n1) { src = in1 + i8; dst = o1 + i8; }
  else {
    int j8 = i8 - n1;
    if (j8 >= n2) return;
    src = in2 + j8; dst = o2 + j8;
  }
  f32x4 a = *(const f32x4*)src;
  f32x4 b = *(const f32x4*)(src + 4);
  union { short s[8]; f32x4 v; } pk;
#pragma unroll
  for (int u = 0; u < 4; ++u) { pk.s[u] = (short)f2bf(a[u]); pk.s[u + 4] = (short)f2bf(b[u]); }
  *(f32x4*)dst = pk.v;
}

// ------ fused channel-RMSNorm + transpose: x[b][c][l] -> xt[b][l][c] -------
__global__ __launch_bounds__(256) void fused_norm_transpose(
    const float* __restrict__ x, const float* __restrict__ g,
    bfr_t* __restrict__ xt) {
  __shared__ float tile[64][65];
  __shared__ float red[4][64];
  __shared__ float invn_s[64];
  int b = blockIdx.y, l0 = blockIdx.x * 64;
  int t = threadIdx.x, ll = t & 63, cg = t >> 6;
  const float* xb = x + (size_t)b * CC * LL + l0;
  float vals[8][16];
  float ss = 0.f;
#pragma unroll
  for (int ch = 0; ch < 8; ++ch) {
    int c0 = ch * 64;
#pragma unroll
    for (int i = 0; i < 16; ++i) {
      int c = i * 4 + cg;                       // chunk-local channel
      float v = xb[(size_t)(c0 + c) * LL + ll];
      vals[ch][i] = v;
      ss += v * v;
    }
  }
  red[cg][ll] = ss;
  __syncthreads();
  if (cg == 0) {
    float s = red[0][ll] + red[1][ll] + red[2][ll] + red[3][ll];
    invn_s[ll] = SQRT_C / fmaxf(sqrtf(s), 1e-12f);
  }
  __syncthreads();
  int lw = t >> 2, ccw = (t & 3) * 16;
  float iv = invn_s[lw];
#pragma unroll
  for (int ch = 0; ch < 8; ++ch) {
    int c0 = ch * 64;
#pragma unroll
    for (int i = 0; i < 16; ++i) tile[i * 4 + cg][ll] = vals[ch][i];
    __syncthreads();
    union { short s[16]; f32x4 v[2]; } pk;
#pragma unroll
    for (int u = 0; u < 16; ++u) {
      int c = ccw + u;
      pk.s[u] = (short)f2bf(tile[c][lw] * g[c0 + c] * iv);
    }
    bfr_t* dst = xt + ((size_t)b * LL + l0 + lw) * CC + c0 + ccw;
    *(f32x4*)dst = pk.v[0];
    *(f32x4*)(dst + 8) = pk.v[1];
    __syncthreads();
  }
}

// ------------- 256x256 register-pipelined sub-phase bf16 GEMM --------------
// (round-5 structure, best measured). C[b][m][n] = sum_k A[m][k]*Bt[b][n][k].
#define NT 8                                      // K-tiles (K=512, BK=64)

__device__ __forceinline__ void stage_half(const bfr_t* g, short* l, int wid) {
  load_lds16(g + (size_t)wid * 8192,        l + wid * 1024);
  load_lds16(g + (size_t)wid * 8192 + 4096, l + wid * 1024 + 512);
}

#define CFENCE asm volatile("" ::: "memory")
#define LGKM0 asm volatile("s_waitcnt lgkmcnt(0)" ::: "memory")
#define VMC0  asm volatile("s_waitcnt vmcnt(0)" ::: "memory")
#define SB    __builtin_amdgcn_sched_barrier(0)
#define BAR   do { CFENCE; __builtin_amdgcn_s_barrier(); CFENCE; } while (0)
#define PRIO1 __builtin_amdgcn_s_setprio(1)
#define PRIO0 __builtin_amdgcn_s_setprio(0)

#define DSR(dst, addr, LIT) \
  asm volatile("ds_read_b128 %0, %1 offset:" #LIT : "=v"(dst) : "v"(addr))

#define RD_A(S, L0, L1, L2, L3) do {           \
    DSR(S[0], aAs0, L0); DSR(S[1], aAs1, L0);  \
    DSR(S[2], aAs0, L1); DSR(S[3], aAs1, L1);  \
    DSR(S[4], aAs0, L2); DSR(S[5], aAs1, L2);  \
    DSR(S[6], aAs0, L3); DSR(S[7], aAs1, L3); } while (0)
#define RD_B(S, L0, L1) do {                   \
    DSR(S[0], bBs0, L0); DSR(S[1], bBs1, L0);  \
    DSR(S[2], bBs0, L1); DSR(S[3], bBs1, L1); } while (0)

#define MMA8(QM, QN, AS, BS) do {                                            \
    _Pragma("unroll") for (int i_ = 0; i_ < 4; ++i_)                         \
      _Pragma("unroll") for (int j_ = 0; j_ < 2; ++j_) {                     \
        acc[(QM)*4+i_][(QN)*2+j_] = __builtin_amdgcn_mfma_f32_16x16x32_bf16( \
            AS[i_*2+0], BS[j_*2+0], acc[(QM)*4+i_][(QN)*2+j_], 0, 0, 0);     \
        acc[(QM)*4+i_][(QN)*2+j_] = __builtin_amdgcn_mfma_f32_16x16x32_bf16( \
            AS[i_*2+1], BS[j_*2+1], acc[(QM)*4+i_][(QN)*2+j_], 0, 0, 0);     \
      }                                                                      \
  } while (0)

#define STAGE_T(J, D) do {                                                   \
    stage_half(pA0 + (J) * 64, As + (D) * 16384, wid);                       \
    stage_half(pA1 + (J) * 64, As + (D) * 16384 + 8192, wid);                \
    stage_half(pB0 + (J) * 64, Bs + (D) * 16384, wid);                       \
    stage_half(pB1 + (J) * 64, Bs + (D) * 16384 + 8192, wid);                \
  } while (0)

#define TILE_E(KT) do {                                                      \
    PRIO1; RD_B(bS1, 4096, 6144); MMA8(0, 0, aS0, bS0); PRIO0; LGKM0; SB;    \
    PRIO1; RD_A(aS1, 8192, 10240, 12288, 14336); MMA8(0, 1, aS0, bS1);      \
    PRIO0; LGKM0; SB;                                                        \
    if ((KT) < 7) { VMC0; }                                                  \
    BAR;                                                                     \
    if ((KT) <= 5) STAGE_T((KT) + 2, 0);                                     \
    PRIO1;                                                                   \
    if ((KT) < 7) RD_A(aS0, 32768, 34816, 36864, 38912);                     \
    MMA8(1, 1, aS1, bS1); PRIO0; LGKM0; SB;                                  \
    PRIO1; MMA8(1, 0, aS1, bS0); PRIO0;                                      \
    if ((KT) < 7) RD_B(bS0, 32768, 34816);                                   \
    LGKM0; SB;                                                               \
  } while (0)

#define TILE_O(KT) do {                                                      \
    PRIO1; RD_B(bS1, 36864, 38912); MMA8(0, 0, aS0, bS0); PRIO0; LGKM0; SB;  \
    PRIO1; RD_A(aS1, 40960, 43008, 45056, 47104); MMA8(0, 1, aS0, bS1);     \
    PRIO0; LGKM0; SB;                                                        \
    if ((KT) < 7) { VMC0; }                                                  \
    BAR;                                                                     \
    if ((KT) <= 5) STAGE_T((KT) + 2, 1);                                     \
    PRIO1;                                                                   \
    if ((KT) < 7) RD_A(aS0, 0, 2048, 4096, 6144);                            \
    MMA8(1, 1, aS1, bS1); PRIO0; LGKM0; SB;                                  \
    PRIO1; MMA8(1, 0, aS1, bS0); PRIO0;                                      \
    if ((KT) < 7) RD_B(bS0, 0, 2048);                                        \
    LGKM0; SB;                                                               \
  } while (0)

__global__ __launch_bounds__(512, 2) void gemm256(
    const bfr_t* __restrict__ A, const bfr_t* __restrict__ Bt,
    bfr_t* __restrict__ Cout, const float* __restrict__ bias, int M) {
  __shared__ short lds[65536];          // 128 KB
  short* As = lds;                      // [2 buf][2 half][128][64]
  short* Bs = lds + 32768;

  // --- bijective XCD-chunk swizzle (nwg % 8 == 0), y fastest in-chunk ---
  int nwg = gridDim.x;
  int gy = M >> 8;
  int bid = blockIdx.x;
  int logical = (bid & 7) * (nwg >> 3) + (bid >> 3);
  int perz = (LL / 256) * gy;
  int bz = logical / perz;
  int rem = logical - bz * perz;
  int bx = rem / gy;
  int by = rem - bx * gy;

  int m0 = by * 256, n0 = bx * 256;
  int t = threadIdx.x, lane = t & 63, wid = t >> 6;
  int quad = lane >> 4, r16 = lane & 15;
  int wm = wid >> 2, wn = wid & 3;
  int soff = (lane >> 3) * 512 + (((lane & 7) ^ (lane >> 3)) * 8);
  int slot0 = (quad ^ (lane & 7)) * 8;          // k 0..31
  int slot1 = ((4 + quad) ^ (lane & 7)) * 8;    // k 32..63

  unsigned lb = (unsigned)(uintptr_t)(__attribute__((address_space(3))) short*)lds;
  unsigned aAs0 = lb + (unsigned)(wm * 16384 + r16 * 128 + slot0 * 2);
  unsigned aAs1 = lb + (unsigned)(wm * 16384 + r16 * 128 + slot1 * 2);
  unsigned bbase = 65536u + (unsigned)((wn >> 1) * 16384 + ((wn & 1) * 64 + r16) * 128);
  unsigned bBs0 = lb + bbase + (unsigned)(slot0 * 2);
  unsigned bBs1 = lb + bbase + (unsigned)(slot1 * 2);

  const bfr_t* pA0 = A + (size_t)m0 * 512 + soff;
  const bfr_t* pA1 = pA0 + (size_t)128 * 512;
  const bfr_t* pB0 = Bt + (size_t)bz * LL * 512 + (size_t)n0 * 512 + soff;
  const bfr_t* pB1 = pB0 + (size_t)128 * 512;

  f32x4 acc[8][4] = {};
  short8 aS0[8], aS1[8];
  short8 bS0[4], bS1[4];

  STAGE_T(0, 0);
  STAGE_T(1, 1);
  asm volatile("s_waitcnt vmcnt(8)" ::: "memory");   // tile 0 landed
  BAR;
  RD_A(aS0, 0, 2048, 4096, 6144);
  RD_B(bS0, 0, 2048);
  LGKM0; SB;

  TILE_E(0); TILE_O(1); TILE_E(2); TILE_O(3);
  TILE_E(4); TILE_O(5); TILE_E(6); TILE_O(7);

  bfr_t* Cb = Cout + (size_t)bz * M * LL;
  int crow = m0 + wm * 128 + quad * 4;
  int ccol = n0 + wn * 64 + r16;
#pragma unroll
  for (int am = 0; am < 8; ++am) {
    int rbase = crow + (am >> 2) * 64 + (am & 3) * 16;
#pragma unroll
    for (int reg = 0; reg < 4; ++reg) {
      int row = rbase + reg;
      float bi = bias ? bias[row] : 0.f;
#pragma unroll
      for (int an = 0; an < 4; ++an) {
        int col = ccol + (an >> 1) * 32 + (an & 1) * 16;
        Cb[(size_t)row * LL + col] = f2bf(acc[am][an][reg] + bi);
      }
    }
  }
}

// --------- fused Wout GEMM (512x128 tile) + rmsnorm + residual -------------
// o[c][l] = Wout[c][:] . out_t[l][:] + b_out[c]; then per-l rmsnorm over all
// 512 c (block-local: block holds ALL channels), *g, + x, fp32 write.
// 8 waves (4M x 2N), per-wave 128x64. LDS: A[2][512][64] + B[128][64] =144KB.
// grid = (LL/128)*BB = 256 blocks = 1 CU round.
#define WSTAGE_A(KT, DB) do {                                                \
    _Pragma("unroll") for (int u_ = 0; u_ < 8; ++u_)                         \
      load_lds16(gA + (size_t)(wid * 8 + u_) * 8 * 512 + (KT) * 64,          \
                 lds + (DB) * 32768 + (wid * 8 + u_) * 512);                 \
  } while (0)
#define WSTAGE_B(KT) do {                                                    \
    _Pragma("unroll") for (int u_ = 0; u_ < 2; ++u_)                         \
      load_lds16(gB + (size_t)(wid * 2 + u_) * 8 * 512 + (KT) * 64,          \
                 lds + 65536 + (wid * 2 + u_) * 512);                        \
  } while (0)

#define MMA_HF(H, AS) do {                                                   \
    _Pragma("unroll") for (int i_ = 0; i_ < 4; ++i_)                         \
      _Pragma("unroll") for (int j_ = 0; j_ < 4; ++j_) {                     \
        acc[(H)*4+i_][j_] = __builtin_amdgcn_mfma_f32_16x16x32_bf16(         \
            AS[i_*2+0], bS[j_*2+0], acc[(H)*4+i_][j_], 0, 0, 0);             \
        acc[(H)*4+i_][j_] = __builtin_amdgcn_mfma_f32_16x16x32_bf16(         \
            AS[i_*2+1], bS[j_*2+1], acc[(H)*4+i_][j_], 0, 0, 0);             \
      }                                                                      \
  } while (0)

#define WTILE(KT, AB0, AB1) do {                                             \
    DSR(bS[0], bR0, 0);    DSR(bS[1], bR1, 0);                               \
    DSR(bS[2], bR0, 2048); DSR(bS[3], bR1, 2048);                            \
    DSR(bS[4], bR0, 4096); DSR(bS[5], bR1, 4096);                            \
    DSR(bS[6], bR0, 6144); DSR(bS[7], bR1, 6144);                            \
    DSR(aS0[0], AB0, 0);    DSR(aS0[1], AB1, 0);                             \
    DSR(aS0[2], AB0, 2048); DSR(aS0[3], AB1, 2048);                          \
    DSR(aS0[4], AB0, 4096); DSR(aS0[5], AB1, 4096);                          \
    DSR(aS0[6], AB0, 6144); DSR(aS0[7], AB1, 6144);                          \
    LGKM0; SB; BAR;                                                          \
    if ((KT) < 7) { WSTAGE_A((KT) + 1, ((KT) & 1) ^ 1); WSTAGE_B((KT) + 1); }\
    PRIO1; MMA_HF(0, aS0); PRIO0;                                            \
    DSR(aS1[0], AB0, 8192);  DSR(aS1[1], AB1, 8192);                         \
    DSR(aS1[2], AB0, 10240); DSR(aS1[3], AB1, 10240);                        \
    DSR(aS1[4], AB0, 12288); DSR(aS1[5], AB1, 12288);                        \
    DSR(aS1[6], AB0, 14336); DSR(aS1[7], AB1, 14336);                        \
    LGKM0; SB;                                                               \
    PRIO1; MMA_HF(1, aS1); PRIO0;                                            \
    if ((KT) < 7) { VMC0; BAR; }                                             \
  } while (0)

__global__ __launch_bounds__(512, 2) void gemm_wout_norm(
    const bfr_t* __restrict__ A, const bfr_t* __restrict__ Bt,
    const float* __restrict__ bias, const float* __restrict__ g,
    const float* __restrict__ x, float* __restrict__ out) {
  __shared__ short lds[73728];          // 144 KB: A[2][512][64] + B[128][64]
  int bid = blockIdx.x;
  int bz = bid >> 5;                    // batch
  int l0 = (bid & 31) * 128;
  int t = threadIdx.x, lane = t & 63, wid = t >> 6;
  int quad = lane >> 4, r16 = lane & 15;
  int wm = wid >> 1, wn = wid & 1;
  int soff = (lane >> 3) * 512 + (((lane & 7) ^ (lane >> 3)) * 8);
  int slot0 = (quad ^ (lane & 7)) * 16;        // byte offsets
  int slot1 = ((4 + quad) ^ (lane & 7)) * 16;

  unsigned lb = (unsigned)(uintptr_t)(__attribute__((address_space(3))) short*)lds;
  unsigned aR0b0 = lb + (unsigned)(wm * 16384 + r16 * 128 + slot0);
  unsigned aR1b0 = lb + (unsigned)(wm * 16384 + r16 * 128 + slot1);
  unsigned aR0b1 = aR0b0 + 65536u;
  unsigned aR1b1 = aR1b0 + 65536u;
  unsigned bR0 = lb + 131072u + (unsigned)(wn * 8192 + r16 * 128 + slot0);
  unsigned bR1 = lb + 131072u + (unsigned)(wn * 8192 + r16 * 128 + slot1);

  const bfr_t* gA = A + soff;                                   // [512][512]
  const bfr_t* gB = Bt + (size_t)bz * LL * 512 + (size_t)l0 * 512 + soff;

  f32x4 acc[8][4] = {};
  short8 aS0[8], aS1[8], bS[8];

  // prologue: stage tile 0 (A -> buf0, B)
  WSTAGE_A(0, 0);
  WSTAGE_B(0);
  VMC0;
  BAR;

  WTILE(0, aR0b0, aR1b0); WTILE(1, aR0b1, aR1b1);
  WTILE(2, aR0b0, aR1b0); WTILE(3, aR0b1, aR1b1);
  WTILE(4, aR0b0, aR1b0); WTILE(5, aR0b1, aR1b1);
  WTILE(6, aR0b0, aR1b0); WTILE(7, aR0b1, aR1b1);

  // ---- epilogue: rmsnorm over c (all 512 in-block) + residual ----
  __syncthreads();                      // LDS now reusable
  float* redf = (float*)lds;            // [4][128]
  float* invf = (float*)lds + 512;      // [128]
  float ssl[4] = {0.f, 0.f, 0.f, 0.f};
#pragma unroll
  for (int am = 0; am < 8; ++am)
#pragma unroll
    for (int reg = 0; reg < 4; ++reg) {
      int row = wm * 128 + (am >> 2) * 64 + (am & 3) * 16 + quad * 4 + reg;
      float bi = bias[row];
#pragma unroll
      for (int an = 0; an < 4; ++an) {
        float o = acc[am][an][reg] + bi;
        ssl[an] += o * o;
      }
    }
#pragma unroll
  for (int an = 0; an < 4; ++an) {
    ssl[an] += __shfl_xor(ssl[an], 16, 64);
    ssl[an] += __shfl_xor(ssl[an], 32, 64);
  }
  if (quad == 0) {
#pragma unroll
    for (int an = 0; an < 4; ++an)
      redf[wm * 128 + wn * 64 + an * 16 + r16] = ssl[an];
  }
  __syncthreads();
  if (t < 128) {
    float s = redf[t] + redf[128 + t] + redf[256 + t] + redf[384 + t];
    invf[t] = SQRT_C / fmaxf(sqrtf(s), 1e-12f);
  }
  __syncthreads();
  float iv[4];
#pragma unroll
  for (int an = 0; an < 4; ++an) iv[an] = invf[wn * 64 + an * 16 + r16];
  const float* xb = x + (size_t)bz * CC * LL + l0;
  float* ob = out + (size_t)bz * CC * LL + l0;
  int cb = wn * 64 + r16;
#pragma unroll
  for (int am = 0; am < 8; ++am)
#pragma unroll
    for (int reg = 0; reg < 4; ++reg) {
      int row = wm * 128 + (am >> 2) * 64 + (am & 3) * 16 + quad * 4 + reg;
      float bi = bias[row], gr = g[row];
      const float* xr = xb + (size_t)row * LL;
      float* orow = ob + (size_t)row * LL;
#pragma unroll
      for (int an = 0; an < 4; ++an) {
        int col = cb + an * 16;
        orow[col] = (acc[am][an][reg] + bi) * gr * iv[an] + xr[col];
      }
    }
}

// --------- context partials via MFMA: ctx_p[bh][s][d][e], n split 8 ---------
__global__ __launch_bounds__(256) void context_mfma(
    const bfr_t* __restrict__ qkv, float* __restrict__ ctx_p,
    float* __restrict__ ksum_p) {
  __shared__ float red[4][4096];      // 64 KB: per-wave 64x64 partial
  int s = blockIdx.x, bh = blockIdx.y;
  int b = bh >> 3, h = bh & 7;
  int t = threadIdx.x, lane = t & 63, wid = t >> 6;
  int quad = lane >> 4, r = lane & 15;
  const bfr_t* kb = qkv + ((size_t)b * TC + 512 + h * 64) * LL;   // raw k rows
  const bfr_t* vb = qkv + ((size_t)b * TC + 1024 + h * 64) * LL;  // v rows
  int n_base = s * 512 + wid * 128;
  f32x4 acc[4][4] = {};
  float ps[4] = {};
#pragma unroll
  for (int ks = 0; ks < 4; ++ks) {
    int n0 = n_base + ks * 32;
    short8 af[4], bf8[4];
#pragma unroll
    for (int i = 0; i < 4; ++i) {
      union { short s[8]; short8 v8; } uk;
      uk.v8 = *(const short8*)&kb[(size_t)(i * 16 + r) * LL + n0 + quad * 8];
#pragma unroll
      for (int jj = 0; jj < 8; ++jj) {
        float e = __expf(bf2f((bfr_t)uk.s[jj]));
        uk.s[jj] = (short)f2bf(e);
        ps[i] += e;
      }
      af[i] = uk.v8;
      bf8[i] = *(const short8*)&vb[(size_t)(i * 16 + r) * LL + n0 + quad * 8];
    }
#pragma unroll
    for (int i = 0; i < 4; ++i)
#pragma unroll
      for (int j = 0; j < 4; ++j)
        acc[i][j] = __builtin_amdgcn_mfma_f32_16x16x32_bf16(af[i], bf8[j],
                                                            acc[i][j], 0, 0, 0);
  }
#pragma unroll
  for (int i = 0; i < 4; ++i) {
    ps[i] += __shfl_xor(ps[i], 16, 64);
    ps[i] += __shfl_xor(ps[i], 32, 64);
  }
  if (quad == 0) {
#pragma unroll
    for (int i = 0; i < 4; ++i) red[wid][i * 16 + r] = ps[i];
  }
  __syncthreads();
  if (t < 64)
    ksum_p[((size_t)bh * 8 + s) * 64 + t] =
        red[0][t] + red[1][t] + red[2][t] + red[3][t];
  __syncthreads();
#pragma unroll
  for (int i = 0; i < 4; ++i)
#pragma unroll
    for (int j = 0; j < 4; ++j)
#pragma unroll
      for (int reg = 0; reg < 4; ++reg)
        red[wid][(i * 16 + quad * 4 + reg) * 64 + j * 16 + r] = acc[i][j][reg];
  __syncthreads();
  float* out = ctx_p + ((size_t)bh * 8 + s) * 4096;
#pragma unroll
  for (int u = 0; u < 16; ++u) {
    int idx = u * 256 + t;
    out[idx] = red[0][idx] + red[1][idx] + red[2][idx] + red[3][idx];
  }
}

// ------- reduce partials, apply 1/Z -> ctx_bf[bh][d][e] (bf16) --------------
__global__ __launch_bounds__(256) void context_reduce(
    const float* __restrict__ ctx_p, const float* __restrict__ ksum_p,
    bfr_t* __restrict__ ctx_bf) {
  __shared__ float zinv[64];
  int bh = blockIdx.x;
  int t = threadIdx.x;
  if (t < 64) {
    float s = 0.f;
#pragma unroll
    for (int s8 = 0; s8 < 8; ++s8) s += ksum_p[((size_t)bh * 8 + s8) * 64 + t];
    zinv[t] = 1.f / s;
  }
  __syncthreads();
#pragma unroll
  for (int i = 0; i < 16; ++i) {
    int idx = i * 256 + t;            // idx = d*64 + e
    int d = idx >> 6;
    float sum = 0.f;
#pragma unroll
    for (int s = 0; s < 8; ++s) sum += ctx_p[((size_t)bh * 8 + s) * 4096 + idx];
    ctx_bf[(size_t)bh * 4096 + idx] = f2bf(sum * zinv[d]);
  }
}

// --- fused q-softmax + apply: out_t[b][n][h*64+e] = softmax_d(q)^T ctx -----
__global__ __launch_bounds__(256) void apply_fused(
    const bfr_t* __restrict__ qkv, const bfr_t* __restrict__ ctx_bf,
    bfr_t* __restrict__ out_t) {
  int b = blockIdx.z, h = blockIdx.y;
  int t = threadIdx.x, lane = t & 63, wid = t >> 6;
  int quad = lane >> 4, r = lane & 15;
  int n0 = blockIdx.x * 256 + wid * 64;
  const bfr_t* qb = qkv + ((size_t)b * TC + h * 64) * LL;   // q rows [d][n]
  const bfr_t* cb = ctx_bf + (size_t)(b * HH + h) * 4096;   // [d][e]
  float v[4][16];
  float psum[4];
#pragma unroll
  for (int i = 0; i < 4; ++i) {
    float s = 0.f;
#pragma unroll
    for (int ks = 0; ks < 2; ++ks)
#pragma unroll
      for (int jj = 0; jj < 8; ++jj) {
        float q = bf2f(qb[(size_t)(ks * 32 + quad * 8 + jj) * LL + n0 + i * 16 + r]);
        float e = __expf(q);
        v[i][ks * 8 + jj] = e;
        s += e;
      }
    psum[i] = s;
  }
#pragma unroll
  for (int i = 0; i < 4; ++i) {
    psum[i] += __shfl_xor(psum[i], 16, 64);
    psum[i] += __shfl_xor(psum[i], 32, 64);
  }
  short8 af[2][4];
#pragma unroll
  for (int i = 0; i < 4; ++i) {
    float sc = SCALE_Q / psum[i];
#pragma unroll
    for (int ks = 0; ks < 2; ++ks) {
      union { short s[8]; short8 v8; } u;
#pragma unroll
      for (int jj = 0; jj < 8; ++jj) u.s[jj] = (short)f2bf(v[i][ks * 8 + jj] * sc);
      af[ks][i] = u.v8;
    }
  }
  short8 bfrag[2][4];
#pragma unroll
  for (int ks = 0; ks < 2; ++ks)
#pragma unroll
    for (int j = 0; j < 4; ++j) {
      union { short s[8]; short8 v8; } u;
#pragma unroll
      for (int jj = 0; jj < 8; ++jj)
        u.s[jj] = (short)cb[(ks * 32 + quad * 8 + jj) * 64 + j * 16 + r];
      bfrag[ks][j] = u.v8;
    }
  f32x4 acc[4][4] = {};
#pragma unroll
  for (int ks = 0; ks < 2; ++ks)
#pragma unroll
    for (int i = 0; i < 4; ++i)
#pragma unroll
      for (int j = 0; j < 4; ++j)
        acc[i][j] = __builtin_amdgcn_mfma_f32_16x16x32_bf16(af[ks][i], bfrag[ks][j],
                                                            acc[i][j], 0, 0, 0);
  bfr_t* dst = out_t + (size_t)b * LL * 512 + h * 64;
#pragma unroll
  for (int i = 0; i < 4; ++i)
#pragma unroll
    for (int reg = 0; reg < 4; ++reg) {
      int row = n0 + i * 16 + quad * 4 + reg;
#pragma unroll
      for (int j = 0; j < 4; ++j)
        dst[(size_t)row * 512 + j * 16 + r] = f2bf(acc[i][j][reg]);
    }
}

// ---------------------------------------------------------------------------
extern "C" void kernel_launch(void* const* d_in, const int* in_sizes, int n_in,
                              void* d_out, int out_size, void* d_ws,
                              size_t ws_size, hipStream_t stream) {
  const float* x     = (const float*)d_in[0];
  const float* g_in  = (const float*)d_in[1];
  const float* w_qkv = (const float*)d_in[2];
  const float* w_out = (const float*)d_in[3];
  const float* b_out = (const float*)d_in[4];
  const float* g_out = (const float*)d_in[5];
  float* out = (float*)d_out;

  // workspace layout (bytes)
  char* ws = (char*)d_ws;
  const size_t off_wqkv  = 0;                       // 1536*512*2 = 1,572,864
  const size_t off_wout  = 1572864;                 // 512*512*2  =   524,288
  const size_t off_ksump = 2097152;                 // 64*8*64*4  =   131,072
  const size_t off_ctx   = 2260992;                 // 64*64*64*2 =   524,288 (bf16)
  const size_t off_ctxp  = 3309568;                 // 64*8*4096*4 = 8,388,608
  const size_t off_xt    = 11698176;                // 32MB  (xn_t, later out_t)
  const size_t off_qkv   = 45252608;                // 96MB
  const size_t ws_need   = 145915904;
  if (ws_size < ws_need) return;   // insufficient scratch -> fail loudly

  bfr_t* wqkv_bf = (bfr_t*)(ws + off_wqkv);
  bfr_t* wout_bf = (bfr_t*)(ws + off_wout);
  float* ksum_p  = (float*)(ws + off_ksump);
  bfr_t* ctx_bf  = (bfr_t*)(ws + off_ctx);
  float* ctxp    = (float*)(ws + off_ctxp);
  bfr_t* xt      = (bfr_t*)(ws + off_xt);    // xn_t then out_t (disjoint lifetimes)
  bfr_t* qkv     = (bfr_t*)(ws + off_qkv);

  // 1. weights -> bf16 (single vectorized launch)
  conv_bf16_2<<<dim3((1536 * 512 + 512 * 512) / 8 / 256), 256, 0, stream>>>(
      w_qkv, wqkv_bf, 1536 * 512, w_out, wout_bf, 512 * 512);
  // 2. fused input rmsnorm + transpose -> bf16 xt
  fused_norm_transpose<<<dim3(LL / 64, BB), 256, 0, stream>>>(x, g_in, xt);
  // 3. qkv = W_qkv @ xn   (single round-5 dispatch)
  gemm256<<<dim3((LL / 256) * (TC / 256) * BB), 512, 0, stream>>>(wqkv_bf, xt, qkv, nullptr, TC);
  // 4. context = exp(k) v^T via MFMA, reduce + 1/Z -> bf16
  context_mfma<<<dim3(8, BB * HH), 256, 0, stream>>>(qkv, ctxp, ksum_p);
  context_reduce<<<dim3(BB * HH), 256, 0, stream>>>(ctxp, ksum_p, ctx_bf);
  // 5. fused q-softmax + apply -> out_t (xn_t now dead)
  apply_fused<<<dim3(LL / 256, HH, BB), 256, 0, stream>>>(qkv, ctx_bf, xt);
  // 6+7. o = W_out @ out + b_out, rmsnorm + residual fused -> fp32 out
  gemm_wout_norm<<<dim3((LL / 128) * BB), 512, 0, stream>>>(
      wout_bf, xt, b_out, g_out, x, out);
}